// Round 7
// baseline (210.563 us; speedup 1.0000x reference)
//
#include <hip/hip_runtime.h>
#include <hip/hip_bf16.h>

#define NN 8192
#define DD 128

typedef __attribute__((ext_vector_type(4))) float f32x4;
typedef __attribute__((ext_vector_type(8))) short bf16x8;
typedef __attribute__((ext_vector_type(4))) short s16x4;

__device__ __forceinline__ short f2bf(float f) {
  __hip_bfloat16 h = __float2bfloat16(f);
  return __builtin_bit_cast(short, h);
}
__device__ __forceinline__ float bf2f(short s) {
  unsigned u = ((unsigned)(unsigned short)s) << 16;
  return __builtin_bit_cast(float, u);
}

// ---------------------------------------------------------------------------
// Kernel 1: yT[n][k] = sum_d x[k][d] * W[d][n]   (bf16, transposed)
// W (64 KB) staged in LDS once; inner loop is LDS-only.
// ---------------------------------------------------------------------------
__global__ __launch_bounds__(256) void xw_kernel(
    const float* __restrict__ x, const float* __restrict__ W,
    short* __restrict__ yT)
{
  __shared__ float xs[32][129];
  __shared__ float Ws[128 * 128];
  const int t  = threadIdx.x;
  const int k0 = blockIdx.x * 32;

  #pragma unroll
  for (int i = 0; i < 16; ++i) {
    int idx = (i * 256 + t) * 4;
    *(f32x4*)&Ws[idx] = *(const f32x4*)(W + idx);
  }
  #pragma unroll
  for (int i = 0; i < 4; ++i) {
    int idx = i * 256 + t;
    int row = idx >> 5;
    int c4  = (idx & 31) * 4;
    f32x4 v = *(const f32x4*)(x + (size_t)(k0 + row) * DD + c4);
    xs[row][c4 + 0] = v[0]; xs[row][c4 + 1] = v[1];
    xs[row][c4 + 2] = v[2]; xs[row][c4 + 3] = v[3];
  }
  __syncthreads();

  const int kl = t & 31;
  const int g  = t >> 5;
  float acc[16];
  #pragma unroll
  for (int j = 0; j < 16; ++j) acc[j] = 0.f;

  for (int d = 0; d < 128; ++d) {
    float xv = xs[kl][d];
    const float* wr = &Ws[d * 128 + g * 16];
    f32x4 w0 = *(const f32x4*)(wr);
    f32x4 w1 = *(const f32x4*)(wr + 4);
    f32x4 w2 = *(const f32x4*)(wr + 8);
    f32x4 w3 = *(const f32x4*)(wr + 12);
    #pragma unroll
    for (int j = 0; j < 4; ++j) {
      acc[j]      += xv * w0[j];
      acc[4 + j]  += xv * w1[j];
      acc[8 + j]  += xv * w2[j];
      acc[12 + j] += xv * w3[j];
    }
  }
  #pragma unroll
  for (int j = 0; j < 16; ++j) {
    int n = g * 16 + j;
    yT[(size_t)n * NN + k0 + kl] = f2bf(acc[j]);
  }
}

// ---------------------------------------------------------------------------
// Kernel 2 (m13-copy regime: NO LDS, plain dwordx4 register loads, max TLP):
//   part[ks][m][n] = bf16( sum_{k in 512-slice ks} A[m][k]*y[k][n] )
//   degpart[ks][m] = fp32 row-sum of the slice
// grid 2048 = 128 row-groups x 16 k-slices; 256 thr / 4 waves; wave owns
// 16 rows x 512 k. Zero LDS + launch_bounds(256,6) -> ~24 waves/CU, every
// wave issuing independent 16B loads: concurrency comes from TLP, exactly
// like the 6.3 TB/s copy microbenchmark (m13), not from a DMA queue.
// ks = b&15, XCD = b%8 -> XCD x reads only Y slices {x, x+8} = 256 KB,
// L2-resident. A loads cacheable (keep L3 replay hits); part stores nt.
// ---------------------------------------------------------------------------
__global__ __launch_bounds__(256, 6) void gcn_main(
    const float* __restrict__ A, const short* __restrict__ yT,
    short* __restrict__ part, float* __restrict__ degpart)
{
  const int tid = threadIdx.x;
  const int l   = tid & 63;
  const int w   = tid >> 6;              // wave 0..3
  const int ks  = blockIdx.x & 15;       // k-slice; XCD x -> ks in {x, x+8}
  const int mg  = blockIdx.x >> 4;       // 0..127
  const int R0  = mg * 64;
  const int kb  = ks * 512;
  const int l15 = l & 15;
  const int kg  = l >> 4;                // 0..3

  const int arow = R0 + w * 16 + l15;
  const float* ap = A  + (size_t)arow * NN + kb + kg * 8;
  const short* yp = yT + (size_t)l15 * NN + kb + kg * 8;

  f32x4 acc[8];
  #pragma unroll
  for (int n = 0; n < 8; ++n) acc[n] = (f32x4)0.f;
  float deg = 0.f;

  for (int s = 0; s < 16; ++s) {
    const float* a0 = ap + s * 32;
    f32x4 alo = *(const f32x4*)a0;
    f32x4 ahi = *(const f32x4*)(a0 + 4);

    deg += (alo[0] + alo[1]) + (alo[2] + alo[3])
         + (ahi[0] + ahi[1]) + (ahi[2] + ahi[3]);

    bf16x8 a;
    #pragma unroll
    for (int j = 0; j < 4; ++j) {
      a[j]     = f2bf(alo[j]);
      a[4 + j] = f2bf(ahi[j]);
    }

    const short* yk = yp + s * 32;
    #pragma unroll
    for (int h = 0; h < 2; ++h) {        // two halves of 4 -> bounded VGPR
      bf16x8 b0 = *(const bf16x8*)(yk + (size_t)(h * 64 +  0) * NN);
      bf16x8 b1 = *(const bf16x8*)(yk + (size_t)(h * 64 + 16) * NN);
      bf16x8 b2 = *(const bf16x8*)(yk + (size_t)(h * 64 + 32) * NN);
      bf16x8 b3 = *(const bf16x8*)(yk + (size_t)(h * 64 + 48) * NN);
      acc[h*4+0] = __builtin_amdgcn_mfma_f32_16x16x32_bf16(a, b0, acc[h*4+0], 0, 0, 0);
      acc[h*4+1] = __builtin_amdgcn_mfma_f32_16x16x32_bf16(a, b1, acc[h*4+1], 0, 0, 0);
      acc[h*4+2] = __builtin_amdgcn_mfma_f32_16x16x32_bf16(a, b2, acc[h*4+2], 0, 0, 0);
      acc[h*4+3] = __builtin_amdgcn_mfma_f32_16x16x32_bf16(a, b3, acc[h*4+3], 0, 0, 0);
    }
  }

  // degree: lanes {l15, +16, +32, +48} hold kg 0..3 of the same row
  deg += __shfl_xor(deg, 16);
  deg += __shfl_xor(deg, 32);
  if (l < 16)
    degpart[(size_t)ks * NN + R0 + w * 16 + l] = deg;

  // partial C tile -> bf16, non-temporal
  short* pb = part + (size_t)ks * NN * DD + (size_t)(R0 + w * 16) * DD;
  #pragma unroll
  for (int n = 0; n < 8; ++n)
    #pragma unroll
    for (int i = 0; i < 4; ++i)
      __builtin_nontemporal_store(f2bf(acc[n][i]),
          pb + (size_t)(kg * 4 + i) * DD + n * 16 + l15);
}

// ---------------------------------------------------------------------------
// Kernel 3: out[m][n] = (sum_ks part[ks][m][n]) / (sum_ks degpart[ks][m])
// ---------------------------------------------------------------------------
__global__ __launch_bounds__(256) void reduce_kernel(
    const short* __restrict__ part, const float* __restrict__ degpart,
    float* __restrict__ out)
{
  const int idx = blockIdx.x * 256 + threadIdx.x;   // 0 .. 8192*32-1
  const int m   = idx >> 5;
  const int c4  = (idx & 31) * 4;

  float s0 = 0.f, s1 = 0.f, s2 = 0.f, s3 = 0.f, d = 0.f;
  #pragma unroll
  for (int ks = 0; ks < 16; ++ks) {
    s16x4 v = *(const s16x4*)(part + (size_t)ks * NN * DD + (size_t)m * DD + c4);
    s0 += bf2f(v[0]); s1 += bf2f(v[1]); s2 += bf2f(v[2]); s3 += bf2f(v[3]);
    d += degpart[(size_t)ks * NN + m];
  }
  f32x4 r;
  r[0] = s0 / d; r[1] = s1 / d; r[2] = s2 / d; r[3] = s3 / d;
  *(f32x4*)(out + (size_t)m * DD + c4) = r;
}

extern "C" void kernel_launch(void* const* d_in, const int* in_sizes, int n_in,
                              void* d_out, int out_size, void* d_ws, size_t ws_size,
                              hipStream_t stream) {
  const float* x = (const float*)d_in[0];   // [8192,128] fp32
  const float* A = (const float*)d_in[1];   // [8192,8192] fp32
  const float* W = (const float*)d_in[2];   // [128,128] fp32
  float* out = (float*)d_out;               // [8192,128] fp32

  // workspace layout
  char* ws = (char*)d_ws;
  short* yT      = (short*)ws;                              // 2 MB  bf16 [128][8192]
  short* part    = (short*)(ws + (2u << 20));               // 32 MB bf16 [16][8192][128]
  float* degpart = (float*)(ws + (2u << 20) + (32u << 20)); // 512 KB fp32 [16][8192]

  xw_kernel<<<256, 256, 0, stream>>>(x, W, yT);
  gcn_main<<<2048, 256, 0, stream>>>(A, yT, part, degpart);
  reduce_kernel<<<1024, 256, 0, stream>>>(part, degpart, out);
}

// Round 9
// 90.942 us; speedup vs baseline: 2.3154x; 2.3154x over previous
//
#include <hip/hip_runtime.h>
#include <hip/hip_bf16.h>

#define NN 8192
#define DD 128

typedef __attribute__((ext_vector_type(4))) float f32x4;
typedef __attribute__((ext_vector_type(16))) float f32x16;
typedef __attribute__((ext_vector_type(8))) short bf16x8;
typedef __attribute__((ext_vector_type(4))) short s16x4;

__device__ __forceinline__ short f2bf(float f) {
  __hip_bfloat16 h = __float2bfloat16(f);
  return __builtin_bit_cast(short, h);
}
__device__ __forceinline__ float bf2f(short s) {
  unsigned u = ((unsigned)(unsigned short)s) << 16;
  return __builtin_bit_cast(float, u);
}

// async global->LDS, 16B/lane; dest = wave-uniform base + lane*16 (linear),
// source per-lane (carries the swizzle).
__device__ __forceinline__ void async_copy16(void* lds, const void* g) {
  __builtin_amdgcn_global_load_lds(
      (const __attribute__((address_space(1))) void*)g,
      (__attribute__((address_space(3))) void*)lds, 16, 0, 0);
}

// ---------------------------------------------------------------------------
// Kernel 1: yT[n][k] = sum_d x[k][d] * W[d][n]   (bf16, transposed)
// ---------------------------------------------------------------------------
__global__ __launch_bounds__(256) void xw_kernel(
    const float* __restrict__ x, const float* __restrict__ W,
    short* __restrict__ yT)
{
  __shared__ float xs[32][129];
  __shared__ float Ws[128 * 128];
  const int t  = threadIdx.x;
  const int k0 = blockIdx.x * 32;

  #pragma unroll
  for (int i = 0; i < 16; ++i) {
    int idx = (i * 256 + t) * 4;
    *(f32x4*)&Ws[idx] = *(const f32x4*)(W + idx);
  }
  #pragma unroll
  for (int i = 0; i < 4; ++i) {
    int idx = i * 256 + t;
    int row = idx >> 5;
    int c4  = (idx & 31) * 4;
    f32x4 v = *(const f32x4*)(x + (size_t)(k0 + row) * DD + c4);
    xs[row][c4 + 0] = v[0]; xs[row][c4 + 1] = v[1];
    xs[row][c4 + 2] = v[2]; xs[row][c4 + 3] = v[3];
  }
  __syncthreads();

  const int kl = t & 31;
  const int g  = t >> 5;
  float acc[16];
  #pragma unroll
  for (int j = 0; j < 16; ++j) acc[j] = 0.f;

  for (int d = 0; d < 128; ++d) {
    float xv = xs[kl][d];
    const float* wr = &Ws[d * 128 + g * 16];
    f32x4 w0 = *(const f32x4*)(wr);
    f32x4 w1 = *(const f32x4*)(wr + 4);
    f32x4 w2 = *(const f32x4*)(wr + 8);
    f32x4 w3 = *(const f32x4*)(wr + 12);
    #pragma unroll
    for (int j = 0; j < 4; ++j) {
      acc[j]      += xv * w0[j];
      acc[4 + j]  += xv * w1[j];
      acc[8 + j]  += xv * w2[j];
      acc[12 + j] += xv * w3[j];
    }
  }
  #pragma unroll
  for (int j = 0; j < 16; ++j) {
    int n = g * 16 + j;
    yT[(size_t)n * NN + k0 + kl] = f2bf(acc[j]);
  }
}

// ---------------------------------------------------------------------------
// Kernel 2: part[ks][m][n] = bf16(sum_{k in 1024-slice} A[m][k] y[k][n])
//           degpart[ks][m]  = fp32 row-sum of the slice
// MFMA 32x32x16 (2x FLOP and 2x rows per 16B fragment vs 16x16x32) to cut
// issue-slots-per-byte ~2x -- R4/R5 were issue-saturated (ds_read+cvt+MFMA
// issue == BW cycle budget), not BW- or latency-bound.
// 256 blocks = 32 mg x 8 ks (ks = b&7 == XCD -> 256KB Y slice L2-resident).
// Block: 512 thr / 8 waves; wave owns 32 rows. K-step 32. LDS 80KB ->
// 2 blocks/CU, 16 waves. DMA staging 5 instr/wave/step (4 A + 1 Y), all
// line-efficient (16B/lane in full 64B lines). vmcnt(5) pacing, dbuf.
// Swizzle rule 21: linear LDS dest; source pre-XOR + read-side XOR.
//   A [256r][8 grp16B]: slot g holds global g^(r&7)
//   Y [128r][4 grp16B]: slot g holds global g^(r&3)
// ---------------------------------------------------------------------------
__global__ __launch_bounds__(512, 4) void gcn_main(
    const float* __restrict__ A, const short* __restrict__ yT,
    short* __restrict__ part, float* __restrict__ degpart)
{
  __shared__ float Abuf[2][256 * 32];   // 2 x 32 KB
  __shared__ short Ybuf[2][128 * 32];   // 2 x  8 KB

  const int tid = threadIdx.x;
  const int l   = tid & 63;
  const int w   = tid >> 6;            // wave 0..7
  const int ks  = blockIdx.x & 7;      // k-slice == XCD id
  const int mg  = blockIdx.x >> 3;     // 0..31
  const int R0  = mg * 256;
  const int kb  = ks * 1024;
  const int l31 = l & 31;
  const int hi  = l >> 5;              // 0/1
  const int wbase = w * 32;

  // --- staging source pointers (pre-swizzled) ---
  const int a_rin  = l >> 3;           // row within 8-row chunk
  const int a_slot = l & 7;
  const float* gA[4];
  #pragma unroll
  for (int i = 0; i < 4; ++i) {
    const int r = wbase + 8 * i + a_rin;
    gA[i] = A + (size_t)(R0 + r) * NN + kb + ((a_slot ^ (r & 7)) << 2);
  }
  const int y_row = w * 16 + (l >> 2);
  const short* gY = yT + (size_t)y_row * NN + kb + (((l & 3) ^ (y_row & 3)) << 3);

  // --- read-side offsets ---
  // A-frag (MFMA-k j, half q): row wbase+l31, groups 4j+2hi+q, XOR (r&7)
  const int arx = l31 & 7;
  int aoff[2][2];
  #pragma unroll
  for (int j = 0; j < 2; ++j)
    #pragma unroll
    for (int q = 0; q < 2; ++q)
      aoff[j][q] = (wbase + l31) * 32 + (((4 * j + 2 * hi + q) ^ arx) << 2);
  // Y-frag (nfrag f, MFMA-k j): row f*32+l31, group 2j+hi, XOR (r&3)
  int yoff[4][2];
  #pragma unroll
  for (int f = 0; f < 4; ++f)
    #pragma unroll
    for (int j = 0; j < 2; ++j)
      yoff[f][j] = (f * 32 + l31) * 32 + (((2 * j + hi) ^ (l31 & 3)) << 3);

  f32x16 acc[4];
  #pragma unroll
  for (int f = 0; f < 4; ++f) acc[f] = (f32x16)0.f;
  float deg = 0.f;

#define STAGE(buf, step) do {                                           \
    const int _k = (step) * 32;                                         \
    _Pragma("unroll")                                                   \
    for (int _i = 0; _i < 4; ++_i)                                      \
      async_copy16(&Abuf[buf][(wbase + 8 * _i) * 32], gA[_i] + _k);     \
    async_copy16(&Ybuf[buf][w * 512], gY + _k);                         \
  } while (0)

  STAGE(0, 0);
  STAGE(1, 1);

  for (int s = 0; s < 32; ++s) {
    __builtin_amdgcn_sched_barrier(0);
    if (s < 31) asm volatile("s_waitcnt vmcnt(5)" ::: "memory");
    else        asm volatile("s_waitcnt vmcnt(0)" ::: "memory");
    __builtin_amdgcn_sched_barrier(0);
    __builtin_amdgcn_s_barrier();
    __builtin_amdgcn_sched_barrier(0);

    const float* Ab = &Abuf[s & 1][0];
    const short* Yb = &Ybuf[s & 1][0];

    #pragma unroll
    for (int j = 0; j < 2; ++j) {
      f32x4 a0 = *(const f32x4*)&Ab[aoff[j][0]];
      f32x4 a1 = *(const f32x4*)&Ab[aoff[j][1]];

      deg += (a0[0] + a0[1]) + (a0[2] + a0[3])
           + (a1[0] + a1[1]) + (a1[2] + a1[3]);

      bf16x8 a;
      #pragma unroll
      for (int e = 0; e < 4; ++e) {
        a[e]     = f2bf(a0[e]);
        a[4 + e] = f2bf(a1[e]);
      }

      #pragma unroll
      for (int f = 0; f < 4; ++f) {
        bf16x8 b = *(const bf16x8*)&Yb[yoff[f][j]];
        acc[f] = __builtin_amdgcn_mfma_f32_32x32x16_bf16(a, b, acc[f], 0, 0, 0);
      }
    }

    __builtin_amdgcn_sched_barrier(0);
    __builtin_amdgcn_s_barrier();
    __builtin_amdgcn_sched_barrier(0);
    if (s + 2 < 32) STAGE(s & 1, s + 2);
  }
#undef STAGE

  // --- degree: lanes l and l+32 hold complementary k-halves of row l31 ---
  deg += __shfl_xor(deg, 32);
  if (l < 32)
    degpart[(size_t)ks * NN + R0 + wbase + l] = deg;

  // --- partial C (32x32 frag layout: col=l31, row=(r&3)+8*(r>>2)+4*hi) ---
  short* pb = part + (size_t)ks * NN * DD + (size_t)(R0 + wbase) * DD;
  #pragma unroll
  for (int f = 0; f < 4; ++f)
    #pragma unroll
    for (int r = 0; r < 16; ++r) {
      const int row = (r & 3) + 8 * (r >> 2) + 4 * hi;
      __builtin_nontemporal_store(f2bf(acc[f][r]),
          pb + (size_t)row * DD + f * 32 + l31);
    }
}

// ---------------------------------------------------------------------------
// Kernel 3: out[m][n] = (sum_ks part[ks][m][n]) / (sum_ks degpart[ks][m])
// ---------------------------------------------------------------------------
__global__ __launch_bounds__(256) void reduce_kernel(
    const short* __restrict__ part, const float* __restrict__ degpart,
    float* __restrict__ out)
{
  const int idx = blockIdx.x * 256 + threadIdx.x;   // 0 .. 8192*32-1
  const int m   = idx >> 5;
  const int c4  = (idx & 31) * 4;

  float s0 = 0.f, s1 = 0.f, s2 = 0.f, s3 = 0.f, d = 0.f;
  #pragma unroll
  for (int ks = 0; ks < 8; ++ks) {
    s16x4 v = *(const s16x4*)(part + (size_t)ks * NN * DD + (size_t)m * DD + c4);
    s0 += bf2f(v[0]); s1 += bf2f(v[1]); s2 += bf2f(v[2]); s3 += bf2f(v[3]);
    d += degpart[(size_t)ks * NN + m];
  }
  f32x4 r;
  r[0] = s0 / d; r[1] = s1 / d; r[2] = s2 / d; r[3] = s3 / d;
  *(f32x4*)(out + (size_t)m * DD + c4) = r;
}

extern "C" void kernel_launch(void* const* d_in, const int* in_sizes, int n_in,
                              void* d_out, int out_size, void* d_ws, size_t ws_size,
                              hipStream_t stream) {
  const float* x = (const float*)d_in[0];   // [8192,128] fp32
  const float* A = (const float*)d_in[1];   // [8192,8192] fp32
  const float* W = (const float*)d_in[2];   // [128,128] fp32
  float* out = (float*)d_out;               // [8192,128] fp32

  // workspace layout
  char* ws = (char*)d_ws;
  short* yT      = (short*)ws;                              // 2 MB  bf16 [128][8192]
  short* part    = (short*)(ws + (2u << 20));               // 16 MB bf16 [8][8192][128]
  float* degpart = (float*)(ws + (2u << 20) + (16u << 20)); // 256 KB fp32 [8][8192]

  xw_kernel<<<256, 256, 0, stream>>>(x, W, yT);
  gcn_main<<<256, 512, 0, stream>>>(A, yT, part, degpart);
  reduce_kernel<<<1024, 256, 0, stream>>>(part, degpart, out);
}